// Round 1
// 452.754 us; speedup vs baseline: 1.0948x; 1.0948x over previous
//
#include <hip/hip_runtime.h>

#define NN 100000
#define NE 1600000
#define NG 512

// ---------- embedding lookup + pre-linear + relu: x1[N,32] ----------
__global__ __launch_bounds__(256) void k_embed(
    const int* __restrict__ nf, const float* __restrict__ semb,
    const float* __restrict__ cemb, const float* __restrict__ pw,
    const float* __restrict__ pb, float* __restrict__ x1)
{
  int gid = blockIdx.x * 256 + threadIdx.x;
  bool valid = gid < NN;
  int i = valid ? gid : NN - 1;
  int sf = nf[2 * i], cf = nf[2 * i + 1];
  float x0[16];
#pragma unroll
  for (int k = 0; k < 8; ++k) x0[k] = semb[sf * 8 + k];
#pragma unroll
  for (int k = 0; k < 8; ++k) x0[8 + k] = cemb[cf * 8 + k];
  float acc[32];
#pragma unroll
  for (int j = 0; j < 32; ++j) acc[j] = pb[j];
#pragma unroll
  for (int k = 0; k < 16; ++k) {
    float xv = x0[k];
#pragma unroll
    for (int j = 0; j < 32; ++j) acc[j] += xv * pw[k * 32 + j];
  }
  if (valid) {
    float4* o = (float4*)(x1 + (size_t)i * 32);
#pragma unroll
    for (int j4 = 0; j4 < 8; ++j4) {
      float4 v;
      v.x = fmaxf(acc[4 * j4 + 0], 0.f);
      v.y = fmaxf(acc[4 * j4 + 1], 0.f);
      v.z = fmaxf(acc[4 * j4 + 2], 0.f);
      v.w = fmaxf(acc[4 * j4 + 3], 0.f);
      o[j4] = v;
    }
  }
}

// ---------- CSR build ----------
__global__ __launch_bounds__(256) void k_deg(const int* __restrict__ ei, int* __restrict__ deg)
{
  int e = blockIdx.x * 256 + threadIdx.x;
  if (e < NE) atomicAdd(&deg[ei[NE + e]], 1);
}

__global__ __launch_bounds__(1024) void k_scan_local(
    const int* __restrict__ deg, int* __restrict__ rs, int* __restrict__ partials)
{
  __shared__ int sm[2][1024];
  int t = threadIdx.x;
  int i = blockIdx.x * 1024 + t;
  int v = (i < NN) ? deg[i] : 0;
  sm[0][t] = v;
  __syncthreads();
  int cur = 0;
#pragma unroll
  for (int off = 1; off < 1024; off <<= 1) {
    int add = (t >= off) ? sm[cur][t - off] : 0;
    int nv = sm[cur][t] + add;
    sm[cur ^ 1][t] = nv;
    __syncthreads();
    cur ^= 1;
  }
  int inc = sm[cur][t];
  if (i < NN) rs[i] = inc - v;  // exclusive scan
  if (t == 1023) partials[blockIdx.x] = inc;
}

__global__ __launch_bounds__(128) void k_scan_part(
    const int* __restrict__ partials, int* __restrict__ offs, int nb)
{
  __shared__ int sm[2][128];
  int t = threadIdx.x;
  int v = (t < nb) ? partials[t] : 0;
  sm[0][t] = v;
  __syncthreads();
  int cur = 0;
#pragma unroll
  for (int off = 1; off < 128; off <<= 1) {
    int add = (t >= off) ? sm[cur][t - off] : 0;
    sm[cur ^ 1][t] = sm[cur][t] + add;
    __syncthreads();
    cur ^= 1;
  }
  if (t < nb) offs[t] = sm[cur][t] - v;  // exclusive
}

__global__ __launch_bounds__(1024) void k_scan_add(int* __restrict__ rs, const int* __restrict__ offs)
{
  int i = blockIdx.x * 1024 + threadIdx.x;
  if (i < NN) rs[i] += offs[blockIdx.x];
  if (i == 0) rs[NN] = NE;
}

__global__ __launch_bounds__(256) void k_fill(
    const int* __restrict__ ei, const int* __restrict__ et,
    const int* __restrict__ rs, int* __restrict__ cur, int* __restrict__ ep)
{
  int e = blockIdx.x * 256 + threadIdx.x;
  if (e >= NE) return;
  int d = ei[NE + e];
  int pos = rs[d] + atomicAdd(&cur[d], 1);
  ep[pos] = ei[e] | (et[e] << 17);  // src < 2^17, type in [0,3)
}

// ---------- per-relation mean aggregation: h[d][r][k] = mean_{(s->d,r)} x[s][k] ----------
// wave-per-dst (IN=64) or half-wave-per-dst (IN=32); x reads are coalesced rows
// (L2/L3-resident working set); 4-deep unrolled edge loop for MLP.
template <int IN>
__global__ __launch_bounds__(256) void k_agg(
    const float* __restrict__ x, const int* __restrict__ rs,
    const int* __restrict__ ep, float* __restrict__ h)
{
  constexpr int DPW = 64 / IN;  // dst per wave
  int tid = threadIdx.x;
  int wid = (blockIdx.x * 256 + tid) >> 6;
  int lane = tid & 63;
  int k = lane & (IN - 1);
  int half = lane >> (IN == 64 ? 6 : 5);  // 0, or 0/1 when IN=32
  int d = wid * DPW + half;
  if (d >= NN) return;
  int p0 = rs[d], p1 = rs[d + 1];
  float a0 = 0.f, a1 = 0.f, a2 = 0.f;
  int c0 = 0, c1 = 0, c2 = 0;
  int p = p0;
  for (; p + 4 <= p1; p += 4) {
    int e0 = ep[p + 0];
    int e1 = ep[p + 1];
    int e2 = ep[p + 2];
    int e3 = ep[p + 3];
    float v0 = x[(size_t)(e0 & 0x1FFFF) * IN + k];
    float v1 = x[(size_t)(e1 & 0x1FFFF) * IN + k];
    float v2 = x[(size_t)(e2 & 0x1FFFF) * IN + k];
    float v3 = x[(size_t)(e3 & 0x1FFFF) * IN + k];
    int t0 = e0 >> 17, t1 = e1 >> 17, t2 = e2 >> 17, t3 = e3 >> 17;
    a0 += ((t0 == 0) ? v0 : 0.f) + ((t1 == 0) ? v1 : 0.f) +
          ((t2 == 0) ? v2 : 0.f) + ((t3 == 0) ? v3 : 0.f);
    a1 += ((t0 == 1) ? v0 : 0.f) + ((t1 == 1) ? v1 : 0.f) +
          ((t2 == 1) ? v2 : 0.f) + ((t3 == 1) ? v3 : 0.f);
    a2 += ((t0 == 2) ? v0 : 0.f) + ((t1 == 2) ? v1 : 0.f) +
          ((t2 == 2) ? v2 : 0.f) + ((t3 == 2) ? v3 : 0.f);
    c0 += (t0 == 0) + (t1 == 0) + (t2 == 0) + (t3 == 0);
    c1 += (t0 == 1) + (t1 == 1) + (t2 == 1) + (t3 == 1);
    c2 += (t0 == 2) + (t1 == 2) + (t2 == 2) + (t3 == 2);
  }
  for (; p < p1; ++p) {
    int e = ep[p];
    float v = x[(size_t)(e & 0x1FFFF) * IN + k];
    int t = e >> 17;
    a0 += (t == 0) ? v : 0.f;
    a1 += (t == 1) ? v : 0.f;
    a2 += (t == 2) ? v : 0.f;
    c0 += (t == 0);
    c1 += (t == 1);
    c2 += (t == 2);
  }
  float* hd = h + (size_t)d * 3 * IN;
  hd[0 * IN + k] = a0 / (float)(c0 > 0 ? c0 : 1);
  hd[1 * IN + k] = a1 / (float)(c1 > 0 ? c1 : 1);
  hd[2 * IN + k] = a2 / (float)(c2 > 0 ? c2 : 1);
}

// ---------- dense: y[d] = relu(x[d]@root + bias + sum_r h[d][r]@rel_r) ----------
// j-split x4: each thread computes a 16-wide output chunk (one 64B line).
// Grid = 4x node-blocks -> ~6 blocks/CU (~24 waves/CU) instead of 1.5 blocks/CU.
// blockIdx swizzle: the 4 sibling j-chunk blocks of a node-block are placed 8
// apart so round-robin XCD dispatch lands them on the SAME XCD -> x/h rows are
// fetched into that XCD's L2 once and reused by all 4 siblings.
// Weight addresses stay wave-uniform -> s_load_dwordx16 per k; inner loop is
// v_fma with SGPR weight operand.
template <int IN>
__global__ __launch_bounds__(256) void k_mat(
    const float* __restrict__ x, const float* __restrict__ h,
    const float* __restrict__ root, const float* __restrict__ rel,
    const float* __restrict__ bias, float* __restrict__ y)
{
  int bid = blockIdx.x;
  // bid = (super << 5) | (jc << 3) | xcd_slot ; nb = super*8 + xcd_slot
  int jc = (bid >> 3) & 3;
  int nb = ((bid >> 5) << 3) | (bid & 7);
  int gid = nb * 256 + threadIdx.x;
  bool valid = gid < NN;
  int i = valid ? gid : NN - 1;
  int j0 = jc * 16;

  float acc[16];
#pragma unroll
  for (int j = 0; j < 16; ++j) acc[j] = bias[j0 + j];

  // m = 0: root with the node's own row
  {
    const float4* S4 = (const float4*)(x + (size_t)i * IN);
#pragma unroll
    for (int k4 = 0; k4 < IN / 4; ++k4) {
      float4 sv = S4[k4];
#pragma unroll
      for (int kk = 0; kk < 4; ++kk) {
        float sk = ((const float*)&sv)[kk];
        const float* w = root + (size_t)(k4 * 4 + kk) * 64 + j0;
#pragma unroll
        for (int j = 0; j < 16; ++j) acc[j] = fmaf(sk, w[j], acc[j]);
      }
    }
  }
  // m = 1..3: rel_m with aggregated means
#pragma unroll
  for (int m = 0; m < 3; ++m) {
    const float4* S4 = (const float4*)(h + ((size_t)i * 3 + m) * IN);
    const float* W = rel + (size_t)m * IN * 64;
#pragma unroll
    for (int k4 = 0; k4 < IN / 4; ++k4) {
      float4 sv = S4[k4];
#pragma unroll
      for (int kk = 0; kk < 4; ++kk) {
        float sk = ((const float*)&sv)[kk];
        const float* w = W + (size_t)(k4 * 4 + kk) * 64 + j0;
#pragma unroll
        for (int j = 0; j < 16; ++j) acc[j] = fmaf(sk, w[j], acc[j]);
      }
    }
  }
  if (valid) {
    float4* o = (float4*)(y + (size_t)i * 64 + j0);
#pragma unroll
    for (int j4 = 0; j4 < 4; ++j4) {
      float4 v;
      v.x = fmaxf(acc[4 * j4 + 0], 0.f);
      v.y = fmaxf(acc[4 * j4 + 1], 0.f);
      v.z = fmaxf(acc[4 * j4 + 2], 0.f);
      v.w = fmaxf(acc[4 * j4 + 3], 0.f);
      o[j4] = v;
    }
  }
}

// ---------- mean pool over sorted batch ids (run-length reduce, then atomic) ----------
__global__ __launch_bounds__(256) void k_pool(
    const float* __restrict__ x3, const int* __restrict__ batch,
    float* __restrict__ pooled, float* __restrict__ gcnt)
{
  int gwave = (blockIdx.x * 256 + threadIdx.x) >> 6;
  int lane = threadIdx.x & 63;
  int n0 = gwave * 64;
  if (n0 >= NN) return;
  int n1 = n0 + 64 < NN ? n0 + 64 : NN;
  int gcur = batch[n0];
  float acc = 0.f;
  int run = 0;
  for (int n = n0; n < n1; ++n) {
    int g = batch[n];
    if (g != gcur) {
      atomicAdd(&pooled[gcur * 64 + lane], acc);
      if (lane == 0) atomicAdd(&gcnt[gcur], (float)run);
      acc = 0.f; run = 0; gcur = g;
    }
    acc += x3[(size_t)n * 64 + lane];
    ++run;
  }
  atomicAdd(&pooled[gcur * 64 + lane], acc);
  if (lane == 0) atomicAdd(&gcnt[gcur], (float)run);
}

// ---------- classifier ----------
__global__ __launch_bounds__(256) void k_cls(
    const float* __restrict__ pooled, const float* __restrict__ gcnt,
    const float* __restrict__ cw, const float* __restrict__ cb, float* __restrict__ out)
{
  int t = blockIdx.x * 256 + threadIdx.x;
  if (t >= NG * 10) return;
  int g = t / 10, c = t % 10;
  float cf = fmaxf(gcnt[g], 1.f);
  float acc = cb[c];
#pragma unroll 8
  for (int k = 0; k < 64; ++k)
    acc += (pooled[g * 64 + k] / cf) * cw[k * 10 + c];
  out[t] = acc;
}

extern "C" void kernel_launch(void* const* d_in, const int* in_sizes, int n_in,
                              void* d_out, int out_size, void* d_ws, size_t ws_size,
                              hipStream_t stream)
{
  const int* nf = (const int*)d_in[0];
  const int* ei = (const int*)d_in[1];
  const int* et = (const int*)d_in[2];
  const int* batch = (const int*)d_in[3];
  const float* semb = (const float*)d_in[4];
  const float* cemb = (const float*)d_in[5];
  const float* pw = (const float*)d_in[6];
  const float* pb = (const float*)d_in[7];
  const float* root1 = (const float*)d_in[8];
  const float* rel1 = (const float*)d_in[9];
  const float* bias1 = (const float*)d_in[10];
  const float* root2 = (const float*)d_in[11];
  const float* rel2 = (const float*)d_in[12];
  const float* bias2 = (const float*)d_in[13];
  const float* cw = (const float*)d_in[14];
  const float* cb = (const float*)d_in[15];
  float* out = (float*)d_out;

  char* ws = (char*)d_ws;
  size_t off = 0;
  auto alloc = [&](size_t bytes) {
    char* p = ws + off;
    off += (bytes + 255) & ~(size_t)255;
    return p;
  };
  int* deg = (int*)alloc((size_t)NN * 4);        // reused as fill cursor
  int* rs = (int*)alloc((size_t)(NN + 1) * 4);   // row_start
  int* partials = (int*)alloc(512);
  int* offs = (int*)alloc(512);
  int* ep = (int*)alloc((size_t)NE * 4);         // packed (src | type<<17), CSR order
  float* xA = (float*)alloc((size_t)NN * 64 * 4);  // x2
  float* xB = (float*)alloc((size_t)NN * 64 * 4);  // x1 ([N,32]) then x3
  float* h = (float*)alloc((size_t)3 * NN * 64 * 4);  // h[d][r][IN]
  float* pooled = (float*)alloc((size_t)NG * 64 * 4);
  float* gcnt = (float*)alloc((size_t)NG * 4);
  (void)ws_size; (void)in_sizes; (void)n_in; (void)out_size;

  hipMemsetAsync(deg, 0, (size_t)NN * 4, stream);
  k_embed<<<(NN + 255) / 256, 256, 0, stream>>>(nf, semb, cemb, pw, pb, xB);
  k_deg<<<(NE + 255) / 256, 256, 0, stream>>>(ei, deg);
  int nb = (NN + 1023) / 1024;
  k_scan_local<<<nb, 1024, 0, stream>>>(deg, rs, partials);
  k_scan_part<<<1, 128, 0, stream>>>(partials, offs, nb);
  k_scan_add<<<nb, 1024, 0, stream>>>(rs, offs);
  hipMemsetAsync(deg, 0, (size_t)NN * 4, stream);  // cursor := 0
  k_fill<<<(NE + 255) / 256, 256, 0, stream>>>(ei, et, rs, deg, ep);

  // node-blocks padded to a multiple of 8 so the j-chunk/XCD swizzle is clean
  int nblk = (NN + 255) / 256;          // 391
  int nblk8 = (nblk + 7) & ~7;          // 392
  int matgrid = nblk8 * 4;              // 1568

  // layer 1: x1[N,32] (xB) -> h -> x2[N,64] (xA)
  k_agg<32><<<(NN / 2 + 3) / 4 + 1, 256, 0, stream>>>(xB, rs, ep, h);
  k_mat<32><<<matgrid, 256, 0, stream>>>(xB, h, root1, rel1, bias1, xA);
  // layer 2: x2 (xA) -> h -> x3 (xB)
  k_agg<64><<<(NN + 3) / 4, 256, 0, stream>>>(xA, rs, ep, h);
  k_mat<64><<<matgrid, 256, 0, stream>>>(xA, h, root2, rel2, bias2, xB);

  hipMemsetAsync(pooled, 0, (size_t)NG * 64 * 4, stream);
  hipMemsetAsync(gcnt, 0, (size_t)NG * 4, stream);
  int nwaves = (NN + 63) / 64;
  k_pool<<<(nwaves + 3) / 4, 256, 0, stream>>>(xB, batch, pooled, gcnt);
  k_cls<<<(NG * 10 + 255) / 256, 256, 0, stream>>>(pooled, gcnt, cw, cb, out);
}

// Round 2
// 340.098 us; speedup vs baseline: 1.4574x; 1.3312x over previous
//
#include <hip/hip_runtime.h>

#define NN 100000
#define NE 1600000
#define NG 512

#define BSH 9                         // bucket = dst >> 9 (512 nodes/bucket)
#define NB 196                        // ceil(NN / 512)
#define EPB 8192                      // edges per block in phase A
#define NAB ((NE + EPB - 1) / EPB)    // 196 phase-A blocks
#define CAP 9216                      // LDS staging capacity in kB_build

// ---------- embedding lookup + pre-linear + relu: x1[N,32] ----------
__global__ __launch_bounds__(256) void k_embed(
    const int* __restrict__ nf, const float* __restrict__ semb,
    const float* __restrict__ cemb, const float* __restrict__ pw,
    const float* __restrict__ pb, float* __restrict__ x1)
{
  int gid = blockIdx.x * 256 + threadIdx.x;
  bool valid = gid < NN;
  int i = valid ? gid : NN - 1;
  int sf = nf[2 * i], cf = nf[2 * i + 1];
  float x0[16];
#pragma unroll
  for (int k = 0; k < 8; ++k) x0[k] = semb[sf * 8 + k];
#pragma unroll
  for (int k = 0; k < 8; ++k) x0[8 + k] = cemb[cf * 8 + k];
  float acc[32];
#pragma unroll
  for (int j = 0; j < 32; ++j) acc[j] = pb[j];
#pragma unroll
  for (int k = 0; k < 16; ++k) {
    float xv = x0[k];
#pragma unroll
    for (int j = 0; j < 32; ++j) acc[j] += xv * pw[k * 32 + j];
  }
  if (valid) {
    float4* o = (float4*)(x1 + (size_t)i * 32);
#pragma unroll
    for (int j4 = 0; j4 < 8; ++j4) {
      float4 v;
      v.x = fmaxf(acc[4 * j4 + 0], 0.f);
      v.y = fmaxf(acc[4 * j4 + 1], 0.f);
      v.z = fmaxf(acc[4 * j4 + 2], 0.f);
      v.w = fmaxf(acc[4 * j4 + 3], 0.f);
      o[j4] = v;
    }
  }
}

// ---------- CSR build via bucketed counting sort ----------
// Replaces k_deg + 3-kernel scan + k_fill. The old k_fill scattered 4B stores
// to random CSR slots: every store dirtied a 64B line written by 16 different
// edges on different XCDs -> 106 MB HBM writes for a 6.4 MB array. Here all
// scatter is confined to regions owned by one workgroup (full-line writeback).

// Phase A1: per-bucket edge counts (LDS histogram, 1 global atomic/bucket/block)
__global__ __launch_bounds__(256) void kA_count(
    const int* __restrict__ ei, int* __restrict__ bkt_cnt)
{
  __shared__ int lh[NB];
  for (int b = threadIdx.x; b < NB; b += 256) lh[b] = 0;
  __syncthreads();
  int base = blockIdx.x * EPB;
#pragma unroll
  for (int i = 0; i < EPB / 256; ++i) {
    int e = base + i * 256 + threadIdx.x;
    if (e < NE) atomicAdd(&lh[ei[NE + e] >> BSH], 1);
  }
  __syncthreads();
  for (int b = threadIdx.x; b < NB; b += 256)
    if (lh[b]) atomicAdd(&bkt_cnt[b], lh[b]);
}

// Phase A2: exclusive scan over the 196 bucket counts -> base + cursor
__global__ __launch_bounds__(256) void kA_scan(
    const int* __restrict__ bkt_cnt, int* __restrict__ bkt_base,
    int* __restrict__ bkt_cur)
{
  __shared__ int sm[2][256];
  int t = threadIdx.x;
  int v = (t < NB) ? bkt_cnt[t] : 0;
  sm[0][t] = v;
  __syncthreads();
  int cur = 0;
#pragma unroll
  for (int off = 1; off < 256; off <<= 1) {
    int add = (t >= off) ? sm[cur][t - off] : 0;
    sm[cur ^ 1][t] = sm[cur][t] + add;
    __syncthreads();
    cur ^= 1;
  }
  if (t < NB) {
    int ex = sm[cur][t] - v;
    bkt_base[t] = ex;
    bkt_cur[t] = ex;
  }
  if (t == 0) bkt_base[NB] = NE;
}

// Phase A3: bin edges by bucket. Each block stages 8192 packed edges in LDS,
// reserves ONE contiguous run per bucket (single atomicAdd), then writes each
// run as a dense burst from this CU -> mostly full 64B lines.
// pack: src(0-16) | type(17-18) | dst&511 (19-27)
__global__ __launch_bounds__(256) void kA_scatter(
    const int* __restrict__ ei, const int* __restrict__ et,
    int* __restrict__ bkt_cur, int* __restrict__ binned)
{
  __shared__ int packA[EPB];
  __shared__ unsigned char bktA[EPB];
  __shared__ int lh[NB], grun[NB], lcur[NB];
  for (int b = threadIdx.x; b < NB; b += 256) { lh[b] = 0; lcur[b] = 0; }
  __syncthreads();
  int base = blockIdx.x * EPB;
#pragma unroll
  for (int i = 0; i < EPB / 256; ++i) {
    int p = i * 256 + threadIdx.x;
    int e = base + p;
    if (e < NE) {
      int src = ei[e], dst = ei[NE + e], ty = et[e];
      int b = dst >> BSH;
      packA[p] = src | (ty << 17) | ((dst & 511) << 19);
      bktA[p] = (unsigned char)b;
      atomicAdd(&lh[b], 1);
    } else {
      bktA[p] = 255;
    }
  }
  __syncthreads();
  for (int b = threadIdx.x; b < NB; b += 256)
    grun[b] = lh[b] ? atomicAdd(&bkt_cur[b], lh[b]) : 0;
  __syncthreads();
#pragma unroll
  for (int i = 0; i < EPB / 256; ++i) {
    int p = i * 256 + threadIdx.x;
    int b = bktA[p];
    if (b != 255) {
      int off = atomicAdd(&lcur[b], 1);
      binned[grun[b] + off] = packA[p];
    }
  }
}

// Phase B: one workgroup per bucket. Owns an exclusive contiguous slice of ep.
// LDS degree histogram over its <=512 nodes -> LDS scan -> writes rs directly
// (replaces k_deg + global scan) -> fills ep via LDS cursors. All ep writes
// land in a ~32KB region written wholesale by this CU -> full-line writeback.
__global__ __launch_bounds__(512) void kB_build(
    const int* __restrict__ bkt_base, const int* __restrict__ binned,
    int* __restrict__ rs, int* __restrict__ ep)
{
  __shared__ int stage[CAP];
  __shared__ int ldeg[512], lrs[512], lcur[512];
  __shared__ int sm[2][512];
  int b = blockIdx.x;
  int t = threadIdx.x;
  int p0 = bkt_base[b], p1 = bkt_base[b + 1];
  int cnt = p1 - p0;
  int nodes0 = b << BSH;
  int nnodes = NN - nodes0 < 512 ? NN - nodes0 : 512;
  ldeg[t] = 0;
  lcur[t] = 0;
  __syncthreads();
  // pass 1: stage + per-node degree histogram
  for (int p = t; p < cnt; p += 512) {
    int pk = binned[p0 + p];
    if (p < CAP) stage[p] = pk;
    atomicAdd(&ldeg[(pk >> 19) & 511], 1);
  }
  __syncthreads();
  // exclusive scan of ldeg -> local row starts
  sm[0][t] = ldeg[t];
  __syncthreads();
  int cur = 0;
#pragma unroll
  for (int off = 1; off < 512; off <<= 1) {
    int add = (t >= off) ? sm[cur][t - off] : 0;
    sm[cur ^ 1][t] = sm[cur][t] + add;
    __syncthreads();
    cur ^= 1;
  }
  lrs[t] = p0 + sm[cur][t] - ldeg[t];
  if (t < nnodes) rs[nodes0 + t] = lrs[t];
  if (b == NB - 1 && t == 0) rs[NN] = NE;
  __syncthreads();
  // pass 2: fill ep (exclusive region -> full-line writes)
  for (int p = t; p < cnt; p += 512) {
    int pk = (p < CAP) ? stage[p] : binned[p0 + p];
    int dl = (pk >> 19) & 511;
    int off = atomicAdd(&lcur[dl], 1);
    ep[lrs[dl] + off] = pk & 0x7FFFF;  // keep src|type bits only
  }
}

// ---------- per-relation mean aggregation: h[d][r][k] = mean_{(s->d,r)} x[s][k] ----------
template <int IN>
__global__ __launch_bounds__(256) void k_agg(
    const float* __restrict__ x, const int* __restrict__ rs,
    const int* __restrict__ ep, float* __restrict__ h)
{
  constexpr int DPW = 64 / IN;  // dst per wave
  int tid = threadIdx.x;
  int wid = (blockIdx.x * 256 + tid) >> 6;
  int lane = tid & 63;
  int k = lane & (IN - 1);
  int half = lane >> (IN == 64 ? 6 : 5);  // 0, or 0/1 when IN=32
  int d = wid * DPW + half;
  if (d >= NN) return;
  int p0 = rs[d], p1 = rs[d + 1];
  float a0 = 0.f, a1 = 0.f, a2 = 0.f;
  int c0 = 0, c1 = 0, c2 = 0;
  int p = p0;
  for (; p + 4 <= p1; p += 4) {
    int e0 = ep[p + 0];
    int e1 = ep[p + 1];
    int e2 = ep[p + 2];
    int e3 = ep[p + 3];
    float v0 = x[(size_t)(e0 & 0x1FFFF) * IN + k];
    float v1 = x[(size_t)(e1 & 0x1FFFF) * IN + k];
    float v2 = x[(size_t)(e2 & 0x1FFFF) * IN + k];
    float v3 = x[(size_t)(e3 & 0x1FFFF) * IN + k];
    int t0 = e0 >> 17, t1 = e1 >> 17, t2 = e2 >> 17, t3 = e3 >> 17;
    a0 += ((t0 == 0) ? v0 : 0.f) + ((t1 == 0) ? v1 : 0.f) +
          ((t2 == 0) ? v2 : 0.f) + ((t3 == 0) ? v3 : 0.f);
    a1 += ((t0 == 1) ? v0 : 0.f) + ((t1 == 1) ? v1 : 0.f) +
          ((t2 == 1) ? v2 : 0.f) + ((t3 == 1) ? v3 : 0.f);
    a2 += ((t0 == 2) ? v0 : 0.f) + ((t1 == 2) ? v1 : 0.f) +
          ((t2 == 2) ? v2 : 0.f) + ((t3 == 2) ? v3 : 0.f);
    c0 += (t0 == 0) + (t1 == 0) + (t2 == 0) + (t3 == 0);
    c1 += (t0 == 1) + (t1 == 1) + (t2 == 1) + (t3 == 1);
    c2 += (t0 == 2) + (t1 == 2) + (t2 == 2) + (t3 == 2);
  }
  for (; p < p1; ++p) {
    int e = ep[p];
    float v = x[(size_t)(e & 0x1FFFF) * IN + k];
    int t = e >> 17;
    a0 += (t == 0) ? v : 0.f;
    a1 += (t == 1) ? v : 0.f;
    a2 += (t == 2) ? v : 0.f;
    c0 += (t == 0);
    c1 += (t == 1);
    c2 += (t == 2);
  }
  float* hd = h + (size_t)d * 3 * IN;
  hd[0 * IN + k] = a0 / (float)(c0 > 0 ? c0 : 1);
  hd[1 * IN + k] = a1 / (float)(c1 > 0 ? c1 : 1);
  hd[2 * IN + k] = a2 / (float)(c2 > 0 ? c2 : 1);
}

// ---------- dense: y[d] = relu(x[d]@root + bias + sum_r h[d][r]@rel_r) ----------
// j-split x4: each thread computes a 16-wide output chunk (one 64B line).
// blockIdx swizzle keeps the 4 sibling j-chunk blocks on the same XCD.
template <int IN>
__global__ __launch_bounds__(256) void k_mat(
    const float* __restrict__ x, const float* __restrict__ h,
    const float* __restrict__ root, const float* __restrict__ rel,
    const float* __restrict__ bias, float* __restrict__ y)
{
  int bid = blockIdx.x;
  int jc = (bid >> 3) & 3;
  int nb = ((bid >> 5) << 3) | (bid & 7);
  int gid = nb * 256 + threadIdx.x;
  bool valid = gid < NN;
  int i = valid ? gid : NN - 1;
  int j0 = jc * 16;

  float acc[16];
#pragma unroll
  for (int j = 0; j < 16; ++j) acc[j] = bias[j0 + j];

  {
    const float4* S4 = (const float4*)(x + (size_t)i * IN);
#pragma unroll
    for (int k4 = 0; k4 < IN / 4; ++k4) {
      float4 sv = S4[k4];
#pragma unroll
      for (int kk = 0; kk < 4; ++kk) {
        float sk = ((const float*)&sv)[kk];
        const float* w = root + (size_t)(k4 * 4 + kk) * 64 + j0;
#pragma unroll
        for (int j = 0; j < 16; ++j) acc[j] = fmaf(sk, w[j], acc[j]);
      }
    }
  }
#pragma unroll
  for (int m = 0; m < 3; ++m) {
    const float4* S4 = (const float4*)(h + ((size_t)i * 3 + m) * IN);
    const float* W = rel + (size_t)m * IN * 64;
#pragma unroll
    for (int k4 = 0; k4 < IN / 4; ++k4) {
      float4 sv = S4[k4];
#pragma unroll
      for (int kk = 0; kk < 4; ++kk) {
        float sk = ((const float*)&sv)[kk];
        const float* w = W + (size_t)(k4 * 4 + kk) * 64 + j0;
#pragma unroll
        for (int j = 0; j < 16; ++j) acc[j] = fmaf(sk, w[j], acc[j]);
      }
    }
  }
  if (valid) {
    float4* o = (float4*)(y + (size_t)i * 64 + j0);
#pragma unroll
    for (int j4 = 0; j4 < 4; ++j4) {
      float4 v;
      v.x = fmaxf(acc[4 * j4 + 0], 0.f);
      v.y = fmaxf(acc[4 * j4 + 1], 0.f);
      v.z = fmaxf(acc[4 * j4 + 2], 0.f);
      v.w = fmaxf(acc[4 * j4 + 3], 0.f);
      o[j4] = v;
    }
  }
}

// ---------- mean pool over sorted batch ids (run-length reduce, then atomic) ----------
__global__ __launch_bounds__(256) void k_pool(
    const float* __restrict__ x3, const int* __restrict__ batch,
    float* __restrict__ pooled, float* __restrict__ gcnt)
{
  int gwave = (blockIdx.x * 256 + threadIdx.x) >> 6;
  int lane = threadIdx.x & 63;
  int n0 = gwave * 64;
  if (n0 >= NN) return;
  int n1 = n0 + 64 < NN ? n0 + 64 : NN;
  int gcur = batch[n0];
  float acc = 0.f;
  int run = 0;
  for (int n = n0; n < n1; ++n) {
    int g = batch[n];
    if (g != gcur) {
      atomicAdd(&pooled[gcur * 64 + lane], acc);
      if (lane == 0) atomicAdd(&gcnt[gcur], (float)run);
      acc = 0.f; run = 0; gcur = g;
    }
    acc += x3[(size_t)n * 64 + lane];
    ++run;
  }
  atomicAdd(&pooled[gcur * 64 + lane], acc);
  if (lane == 0) atomicAdd(&gcnt[gcur], (float)run);
}

// ---------- classifier ----------
__global__ __launch_bounds__(256) void k_cls(
    const float* __restrict__ pooled, const float* __restrict__ gcnt,
    const float* __restrict__ cw, const float* __restrict__ cb, float* __restrict__ out)
{
  int t = blockIdx.x * 256 + threadIdx.x;
  if (t >= NG * 10) return;
  int g = t / 10, c = t % 10;
  float cf = fmaxf(gcnt[g], 1.f);
  float acc = cb[c];
#pragma unroll 8
  for (int k = 0; k < 64; ++k)
    acc += (pooled[g * 64 + k] / cf) * cw[k * 10 + c];
  out[t] = acc;
}

extern "C" void kernel_launch(void* const* d_in, const int* in_sizes, int n_in,
                              void* d_out, int out_size, void* d_ws, size_t ws_size,
                              hipStream_t stream)
{
  const int* nf = (const int*)d_in[0];
  const int* ei = (const int*)d_in[1];
  const int* et = (const int*)d_in[2];
  const int* batch = (const int*)d_in[3];
  const float* semb = (const float*)d_in[4];
  const float* cemb = (const float*)d_in[5];
  const float* pw = (const float*)d_in[6];
  const float* pb = (const float*)d_in[7];
  const float* root1 = (const float*)d_in[8];
  const float* rel1 = (const float*)d_in[9];
  const float* bias1 = (const float*)d_in[10];
  const float* root2 = (const float*)d_in[11];
  const float* rel2 = (const float*)d_in[12];
  const float* bias2 = (const float*)d_in[13];
  const float* cw = (const float*)d_in[14];
  const float* cb = (const float*)d_in[15];
  float* out = (float*)d_out;

  char* ws = (char*)d_ws;
  size_t off = 0;
  auto alloc = [&](size_t bytes) {
    char* p = ws + off;
    off += (bytes + 255) & ~(size_t)255;
    return p;
  };
  int* bkt_cnt = (int*)alloc((size_t)NB * 4);
  int* bkt_base = (int*)alloc((size_t)(NB + 1) * 4);
  int* bkt_cur = (int*)alloc((size_t)NB * 4);
  int* rs = (int*)alloc((size_t)(NN + 1) * 4);     // row_start
  int* ep = (int*)alloc((size_t)NE * 4);           // packed (src | type<<17), CSR order
  float* xA = (float*)alloc((size_t)NN * 64 * 4);  // x2
  float* xB = (float*)alloc((size_t)NN * 64 * 4);  // x1 ([N,32]) then x3
  float* h = (float*)alloc((size_t)3 * NN * 64 * 4);  // h[d][r][IN]
  float* pooled = (float*)alloc((size_t)NG * 64 * 4);
  float* gcnt = (float*)alloc((size_t)NG * 4);
  int* binned = (int*)h;  // phase-A output; consumed by kB_build before k_agg writes h
  (void)ws_size; (void)in_sizes; (void)n_in; (void)out_size;

  hipMemsetAsync(bkt_cnt, 0, (size_t)NB * 4, stream);
  k_embed<<<(NN + 255) / 256, 256, 0, stream>>>(nf, semb, cemb, pw, pb, xB);

  // CSR build: bucketed counting sort (no k_deg, no global scan, no random scatter)
  kA_count<<<NAB, 256, 0, stream>>>(ei, bkt_cnt);
  kA_scan<<<1, 256, 0, stream>>>(bkt_cnt, bkt_base, bkt_cur);
  kA_scatter<<<NAB, 256, 0, stream>>>(ei, et, bkt_cur, binned);
  kB_build<<<NB, 512, 0, stream>>>(bkt_base, binned, rs, ep);

  // node-blocks padded to a multiple of 8 so the j-chunk/XCD swizzle is clean
  int nblk = (NN + 255) / 256;          // 391
  int nblk8 = (nblk + 7) & ~7;          // 392
  int matgrid = nblk8 * 4;              // 1568

  // layer 1: x1[N,32] (xB) -> h -> x2[N,64] (xA)
  k_agg<32><<<(NN / 2 + 3) / 4 + 1, 256, 0, stream>>>(xB, rs, ep, h);
  k_mat<32><<<matgrid, 256, 0, stream>>>(xB, h, root1, rel1, bias1, xA);
  // layer 2: x2 (xA) -> h -> x3 (xB)
  k_agg<64><<<(NN + 3) / 4, 256, 0, stream>>>(xA, rs, ep, h);
  k_mat<64><<<matgrid, 256, 0, stream>>>(xA, h, root2, rel2, bias2, xB);

  hipMemsetAsync(pooled, 0, (size_t)NG * 64 * 4, stream);
  hipMemsetAsync(gcnt, 0, (size_t)NG * 4, stream);
  int nwaves = (NN + 63) / 64;
  k_pool<<<(nwaves + 3) / 4, 256, 0, stream>>>(xB, batch, pooled, gcnt);
  k_cls<<<(NG * 10 + 255) / 256, 256, 0, stream>>>(pooled, gcnt, cw, cb, out);
}